// Round 4
// baseline (20.741 us; speedup 1.0000x reference)
//
#include <hip/hip_runtime.h>

#define IN_DIM   2048
#define OUT_DIM  16384
#define NT       256
#define ROWS     2
#define EPS      1e-12f

// out[b][j] = -scale * rnorm_b * WHT2048(x[b])[j & 2047] + bias[j]
// FWHT stages commute; pass order bits{8-10},{3-5},{6-7},{0-2} makes the load
// coalesced-b32 and the final layout 8-consecutive-per-thread (direct b128
// stores). swz keeps every LDS boundary at <=2-way bank aliasing.
//
// KEY (R4): __syncthreads() drains vmcnt(0) -> serializes row-r stores against
// row-r+1 FWHT. Replace with {s_waitcnt lgkmcnt(0); s_barrier} so global
// stores stay in flight across barriers (LDS-only correctness requirement).

__device__ __forceinline__ int swz(int e) { return e ^ (((e >> 6) & 7) << 3); }

__device__ __forceinline__ void barrier_lds_only() {
    asm volatile("s_waitcnt lgkmcnt(0)" ::: "memory");
    __builtin_amdgcn_s_barrier();
}

#define BFLY(m)                                                   \
    _Pragma("unroll")                                             \
    for (int k = 0; k < 8; ++k)                                   \
        if (!(k & (m))) {                                         \
            const float a_ = v[k], b_ = v[k | (m)];               \
            v[k]       = a_ + b_;                                 \
            v[k | (m)] = a_ - b_;                                 \
        }

__global__ __launch_bounds__(NT) void had_fwht_kernel(
    const float* __restrict__ x,
    const float* __restrict__ scale,
    const float* __restrict__ bias,
    float* __restrict__ out)
{
    __shared__ float sA[ROWS][IN_DIM];
    __shared__ float red[ROWS][NT / 64];

    const int g  = blockIdx.x;
    const int t  = threadIdx.x;
    const int wv = t >> 6;

    // ---- prefetch row 0 FIRST (needed soonest): e = (k<<8) | t
    float p[8];
    {
        const float* xr = x + (size_t)(g * ROWS) * IN_DIM;
#pragma unroll
        for (int k = 0; k < 8; ++k) p[k] = xr[(k << 8) + t];
    }

    const float negscale = -scale[0];

    // ---- hoist bias into registers: bj[2*tile+h] = bias4[tile*512 + 2t + h]
    const float4* bias4 = (const float4*)bias;
    float4 bj[16];
#pragma unroll
    for (int i = 0; i < 16; ++i)
        bj[i] = bias4[(i >> 1) * 512 + 2 * t + (i & 1)];

#pragma unroll
    for (int rr = 0; rr < ROWS; ++rr) {
        const int row = g * ROWS + rr;
        float v[8];
#pragma unroll
        for (int k = 0; k < 8; ++k) v[k] = p[k];

        // ---- sum of squares: wave shuffle, cross-wave via red[rr]
        float local = 0.f;
#pragma unroll
        for (int k = 0; k < 8; ++k) local = fmaf(v[k], v[k], local);
#pragma unroll
        for (int off = 32; off > 0; off >>= 1)
            local += __shfl_down(local, off, 64);
        if ((t & 63) == 0) red[rr][wv] = local;

        // ---- pass 1: bits 8..10 (d = 256,512,1024)
        BFLY(1) BFLY(2) BFLY(4)
#pragma unroll
        for (int k = 0; k < 8; ++k) sA[rr][swz((k << 8) | t)] = v[k];

        // ---- prefetch next row BEFORE the barrier (flies under passes 2-4)
        if (rr + 1 < ROWS) {
            const float* xn = x + (size_t)(row + 1) * IN_DIM;
#pragma unroll
            for (int k = 0; k < 8; ++k) p[k] = xn[(k << 8) + t];
        }
        barrier_lds_only();

        // ---- pass 2: bits 3..5; e = (t>>3)<<6 | k<<3 | (t&7)
        const int b1 = ((t >> 3) << 6) | (t & 7);
#pragma unroll
        for (int k = 0; k < 8; ++k) v[k] = sA[rr][swz(b1 | (k << 3))];
        BFLY(1) BFLY(2) BFLY(4)
#pragma unroll
        for (int k = 0; k < 8; ++k) sA[rr][swz(b1 | (k << 3))] = v[k];
        barrier_lds_only();

        const float sumsq = red[rr][0] + red[rr][1] + red[rr][2] + red[rr][3];
        const float c = negscale * rsqrtf(fmaxf(sumsq, EPS));

        // ---- pass 3: bits 6..7; e = (k>>2)<<10 | (t>>6)<<8 | (k&3)<<6 | (t&63)
        const int b2 = ((t >> 6) << 8) | (t & 63);
#pragma unroll
        for (int k = 0; k < 8; ++k)
            v[k] = sA[rr][swz(((k >> 2) << 10) | ((k & 3) << 6) | b2)];
        BFLY(1) BFLY(2)                    // bit 10 already done in pass 1
#pragma unroll
        for (int k = 0; k < 8; ++k)
            sA[rr][swz(((k >> 2) << 10) | ((k & 3) << 6) | b2)] = v[k];
        barrier_lds_only();

        // ---- pass 4: bits 0..2; e = t<<3 | k (swz preserves low 3 bits)
        {
            const int base = swz(t << 3);  // 32B-aligned
            const float4 lo = *(const float4*)&sA[rr][base];
            const float4 hi = *(const float4*)&sA[rr][base + 4];
            v[0] = lo.x; v[1] = lo.y; v[2] = lo.z; v[3] = lo.w;
            v[4] = hi.x; v[5] = hi.y; v[6] = hi.z; v[7] = hi.w;
        }
        BFLY(1) BFLY(2) BFLY(4)

        // ---- stores: out[row][tile*2048 + 8t + k], pure b128 stores
        float4* orow = (float4*)(out + (size_t)row * OUT_DIM);
#pragma unroll
        for (int tile = 0; tile < 8; ++tile) {
            float4 o0, o1;
            o0.x = fmaf(c, v[0], bj[2 * tile].x);
            o0.y = fmaf(c, v[1], bj[2 * tile].y);
            o0.z = fmaf(c, v[2], bj[2 * tile].z);
            o0.w = fmaf(c, v[3], bj[2 * tile].w);
            o1.x = fmaf(c, v[4], bj[2 * tile + 1].x);
            o1.y = fmaf(c, v[5], bj[2 * tile + 1].y);
            o1.z = fmaf(c, v[6], bj[2 * tile + 1].z);
            o1.w = fmaf(c, v[7], bj[2 * tile + 1].w);
            orow[tile * 512 + 2 * t]     = o0;
            orow[tile * 512 + 2 * t + 1] = o1;
        }
    }
}

extern "C" void kernel_launch(void* const* d_in, const int* in_sizes, int n_in,
                              void* d_out, int out_size, void* d_ws, size_t ws_size,
                              hipStream_t stream) {
    const float* x     = (const float*)d_in[0];
    const float* scale = (const float*)d_in[1];
    const float* bias  = (const float*)d_in[2];
    // d_in[3] (dense hadamard) unused: structure exploited in-kernel.
    float* out = (float*)d_out;

    const int batch = in_sizes[0] / IN_DIM;   // 1024
    had_fwht_kernel<<<batch / ROWS, NT, 0, stream>>>(x, scale, bias, out);
}

// Round 5
// 17.955 us; speedup vs baseline: 1.1552x; 1.1552x over previous
//
#include <hip/hip_runtime.h>

#define IN_DIM   2048
#define OUT_DIM  16384
#define NT       256
#define EPS      1e-12f

typedef float f32x4 __attribute__((ext_vector_type(4)));

// out[b][j] = -scale * rnorm_b * WHT2048(x[b])[j & 2047] + bias[j]
// (hadamard = H_16384[:2048,:], H[i][j]=(-1)^popcount(i&j): only j&2047 matters.)
//
// R5 structure: ONE barrier total.
//   - wave-local WHT512 per 512-elem chunk (bits 0-8): in-reg butterflies +
//     two wave-internal LDS round trips (wave64 lockstep => no barrier needed)
//   - barrier (lgkmcnt only)
//   - bits 9-10 fused into the output read (4-term combos in registers)
//   - stores: lane-contiguous float4 (1KiB/instr), nontemporal; bias in regs.

__device__ __forceinline__ int swz(int e) { return e ^ (((e >> 6) & 7) << 3); }

#define BFLY(m)                                                   \
    _Pragma("unroll")                                             \
    for (int k = 0; k < 8; ++k)                                   \
        if (!(k & (m))) {                                         \
            const float a_ = v[k], b_ = v[k | (m)];               \
            v[k]       = a_ + b_;                                 \
            v[k | (m)] = a_ - b_;                                 \
        }

__global__ __launch_bounds__(NT, 4) void had_fwht_kernel(
    const float* __restrict__ x,
    const float* __restrict__ scale,
    const float* __restrict__ bias,
    float* __restrict__ out)
{
    __shared__ float sA[IN_DIM];   // swizzled wave-local shuffle space
    __shared__ float sB[IN_DIM];   // linear, for the fused output read
    __shared__ float red[NT / 64];

    const int b = blockIdx.x;
    const int t = threadIdx.x;
    const int l = t & 63;
    const int w = t >> 6;

    // ---- x row: thread owns elements 8t..8t+7 (= chunk w, lane l, bits0-2=k)
    const float4* xr4 = (const float4*)(x + (size_t)b * IN_DIM);
    const float4 a0 = xr4[2 * t];
    const float4 a1 = xr4[2 * t + 1];

    // ---- bias -> 16 regs (L2-hot after first touch; frees the store window)
    const float4* bias4 = (const float4*)bias;
    float4 bj[16];
#pragma unroll
    for (int i = 0; i < 16; ++i) bj[i] = bias4[t + i * NT];

    const float negscale = -scale[0];

    float v[8] = {a0.x, a0.y, a0.z, a0.w, a1.x, a1.y, a1.z, a1.w};

    // ---- sum of squares: wave shuffle; cross-wave via red[] (read post-barrier)
    float local = 0.f;
#pragma unroll
    for (int k = 0; k < 8; ++k) local = fmaf(v[k], v[k], local);
#pragma unroll
    for (int off = 32; off > 0; off >>= 1)
        local += __shfl_down(local, off, 64);
    if (l == 0) red[w] = local;

    // ---- bits 0-2 in registers
    BFLY(1) BFLY(2) BFLY(4)

    // ---- wave-local round trip 1: write e=8t+k (2x b128), read bits3-5 into k
    {
        const int base = swz(t << 3);            // swz keeps low 3 bits: 16B-aligned
        *(float4*)&sA[base]     = make_float4(v[0], v[1], v[2], v[3]);
        *(float4*)&sA[base + 4] = make_float4(v[4], v[5], v[6], v[7]);
    }
    const int bB = (w << 9) | ((l >> 3) << 6) | (l & 7);
#pragma unroll
    for (int k = 0; k < 8; ++k) v[k] = sA[swz(bB | (k << 3))];
    BFLY(1) BFLY(2) BFLY(4)                      // bits 3-5

    // ---- wave-local round trip 2: write back layout B, read bits6-8 into k
#pragma unroll
    for (int k = 0; k < 8; ++k) sA[swz(bB | (k << 3))] = v[k];
    const int bC = (w << 9) | l;
#pragma unroll
    for (int k = 0; k < 8; ++k) v[k] = sA[swz(bC | (k << 6))];
    BFLY(1) BFLY(2) BFLY(4)                      // bits 6-8

    // ---- final: linear sB at element (w<<9)|(k<<6)|l  (2-way banks, free)
#pragma unroll
    for (int k = 0; k < 8; ++k) sB[bC | (k << 6)] = v[k];

    // ---- the ONLY barrier (LDS drain only)
    asm volatile("s_waitcnt lgkmcnt(0)" ::: "memory");
    __builtin_amdgcn_s_barrier();

    const float sumsq = red[0] + red[1] + red[2] + red[3];
    const float c = negscale * rsqrtf(fmaxf(sumsq, EPS));

    // ---- bits 9-10 fused: G[c] = sB4[(t&127) + c*128]; combos in registers
    const float4* sB4 = (const float4*)sB;
    const int q = t & 127;
    const float4 G0 = sB4[q];
    const float4 G1 = sB4[q + 128];
    const float4 G2 = sB4[q + 256];
    const float4 G3 = sB4[q + 384];

    float4 s01, d01, s23, d23;
    s01.x = G0.x + G1.x; s01.y = G0.y + G1.y; s01.z = G0.z + G1.z; s01.w = G0.w + G1.w;
    d01.x = G0.x - G1.x; d01.y = G0.y - G1.y; d01.z = G0.z - G1.z; d01.w = G0.w - G1.w;
    s23.x = G2.x + G3.x; s23.y = G2.y + G3.y; s23.z = G2.z + G3.z; s23.w = G2.w + G3.w;
    d23.x = G2.x - G3.x; d23.y = G2.y - G3.y; d23.z = G2.z - G3.z; d23.w = G2.w - G3.w;

    // output float4 idx = t + i*256; n = idx&511; c' = n>>7 = (t>>7) + 2*(i&1)
    const bool hi = (t >= 128);
    const float4 A = hi ? d01 : s01;
    const float4 B = hi ? d23 : s23;
    float4 w_e, w_o;
    w_e.x = A.x + B.x; w_e.y = A.y + B.y; w_e.z = A.z + B.z; w_e.w = A.w + B.w;
    w_o.x = A.x - B.x; w_o.y = A.y - B.y; w_o.z = A.z - B.z; w_o.w = A.w - B.w;

    // ---- stores: lane-contiguous 1KiB/instr, nontemporal
    f32x4* orow = (f32x4*)(out + (size_t)b * OUT_DIM);
#pragma unroll
    for (int i = 0; i < 16; ++i) {
        const float4 ws = (i & 1) ? w_o : w_e;
        f32x4 o;
        o.x = fmaf(c, ws.x, bj[i].x);
        o.y = fmaf(c, ws.y, bj[i].y);
        o.z = fmaf(c, ws.z, bj[i].z);
        o.w = fmaf(c, ws.w, bj[i].w);
        __builtin_nontemporal_store(o, &orow[t + i * NT]);
    }
}

extern "C" void kernel_launch(void* const* d_in, const int* in_sizes, int n_in,
                              void* d_out, int out_size, void* d_ws, size_t ws_size,
                              hipStream_t stream) {
    const float* x     = (const float*)d_in[0];
    const float* scale = (const float*)d_in[1];
    const float* bias  = (const float*)d_in[2];
    // d_in[3] (dense hadamard) unused: structure exploited in-kernel.
    float* out = (float*)d_out;

    const int batch = in_sizes[0] / IN_DIM;   // 1024
    had_fwht_kernel<<<batch, NT, 0, stream>>>(x, scale, bias, out);
}